// Round 26
// baseline (18.793 us; speedup 1.0000x reference)
//
#include <hip/hip_runtime.h>
#include <hip/hip_bf16.h>

#define TOKENS 32
#define KDIM   4096
#define NDIM   11008
#define GSZ    64
#define KP     (KDIM/2)          // qweight row length in int32 (2048)
#define NGRP   (KDIM/GSZ)        // 64 groups
#define OUTK   8                 // K-splits across blocks (== 8 XCDs, ob=bi&7)
#define BLK_COLS 128             // 4 colWaves * 32 cols
#define NBLK_C (NDIM/BLK_COLS)   // 86
#define KSLICE (KDIM/OUTK)       // 512 k per block
#define GPW    (KSLICE/2/GSZ)    // 4 groups per wave (2 inner ksegs)
#define PART_ELEMS (TOKENS*NDIM) // 352256

typedef float  f32x4 __attribute__((ext_vector_type(4)));
typedef float  f32x8 __attribute__((ext_vector_type(8)));
typedef int    i32x4 __attribute__((ext_vector_type(4)));
typedef short  s16x8 __attribute__((ext_vector_type(8)));
typedef _Float16 f16x2 __attribute__((ext_vector_type(2)));
typedef _Float16 f16x8 __attribute__((ext_vector_type(8)));

// r26 = r19/r23 (18.1us, best) + ONE change: __builtin_amdgcn_sched_barrier(0)
// after each in-loop LOADG. Mechanism: r11's PMC showed VGPR=44 — the
// compiler re-orders the prefetch's global loads down to right-before-use
// (un-pipelining the 2-deep software pipeline), so each group's 5 loads are
// an exposed serial L2 round-trip. The barrier forbids moving those loads
// past the next COMPUTE, forcing real overlap (load results stay live across
// a COMPUTE -> VGPR should rise to ~90-130). Minimal placement (2/iter;
// m141's regression was from PERVASIVE pinning). If neutral, the K-loop is
// TLP-saturated and the structure is final.
// All other decisions locked by failed alternatives (see r25 history).
__global__ __launch_bounds__(512, 2) void awq_gemm2(
    const int* __restrict__ qw, const float* __restrict__ sc,
    const float* __restrict__ zp, const float* __restrict__ xf,
    _Float16* __restrict__ partial) {
    __shared__ unsigned short xs[TOKENS * KSLICE];   // 32 KB (reused for reduce)

    const int tid  = threadIdx.x;
    const int lane = tid & 63;
    const int wid  = tid >> 6;       // 0..7
    const int cw   = wid & 3;        // colWave
    const int ks   = wid >> 2;       // inner kseg 0..1
    const int ob   = blockIdx.x & 7;         // outer kseg == XCD
    const int bc   = blockIdx.x >> 3;        // col group 0..85
    const int K0   = ob * KSLICE;

    const int col  = lane & 15;
    const int kg   = lane >> 4;                      // k-subgroup 0..3
    const int n0   = bc * BLK_COLS + cw * 32 + col;  // colset-0 column
    const int sh0  = 8 * (n0 & 3);
    const int* qp0 = qw + (n0 >> 2) * KP + kg * 4;   // colset-1 = +4*KP ints

    struct GD { float s0, z0, s1, z1; i32x4 qa0, qa1, qb0, qb1; };

    auto LOADG = [&](GD& d, int gl) {
        gl = gl < GPW ? gl : GPW - 1;                // clamp prefetch overhang
        const int gg = ob * (NGRP / OUTK) + ks * GPW + gl;  // global group
        d.s0 = sc[gg * NDIM + n0];        d.z0 = zp[gg * NDIM + n0];
        d.s1 = sc[gg * NDIM + n0 + 16];   d.z1 = zp[gg * NDIM + n0 + 16];
        const int* q = qp0 + gg * 32;
        d.qa0 = *reinterpret_cast<const i32x4*>(q);
        d.qa1 = *reinterpret_cast<const i32x4*>(q + 16);
        d.qb0 = *reinterpret_cast<const i32x4*>(q + 4 * KP);
        d.qb1 = *reinterpret_cast<const i32x4*>(q + 4 * KP + 16);
    };

    // ---- q-prefetch for groups 0/1 issued BEFORE staging ----
    GD gA, gB;
    LOADG(gA, 0);
    LOADG(gB, 1);

    // ---- stage x slice: f32 global -> f16 swizzled LDS (32KB) ----
#pragma unroll
    for (int it = 0; it < 4; ++it) {
        const int lin  = it * 8192 + tid * 16;       // byte offset in f16 slice
        const int tok  = lin >> 10;
        const int kloc = (lin & 1023) >> 1;
        const float* xp = xf + tok * KDIM + K0 + kloc;
        f32x4 u0 = *reinterpret_cast<const f32x4*>(xp);
        f32x4 u1 = *reinterpret_cast<const f32x4*>(xp + 4);
        s16x8 v;
#pragma unroll
        for (int e = 0; e < 4; ++e) {
            v[e]     = __builtin_bit_cast(short, (_Float16)u0[e]);
            v[e + 4] = __builtin_bit_cast(short, (_Float16)u1[e]);
        }
        *reinterpret_cast<s16x8*>(
            reinterpret_cast<char*>(xs) + (lin ^ ((tok & 7) << 4))) = v;
    }
    __syncthreads();

    f32x4 acc00 = {0,0,0,0}, acc01 = {0,0,0,0};      // [colset][Mtile]
    f32x4 acc10 = {0,0,0,0}, acc11 = {0,0,0,0};

    auto LDSA = [&](int tok, int c) -> f16x8 {       // a-frag from swizzled LDS
        const int inrow = ((c << 6) + (kg << 4)) ^ ((tok & 7) << 4);
        return *reinterpret_cast<const f16x8*>(
            reinterpret_cast<const char*>(xs) + (tok << 10) + inrow);
    };

    const f16x2 m1024 = {(_Float16)(-1024.0f), (_Float16)(-1024.0f)};

    auto DQ = [&](const i32x4& q, f16x2 s2, f16x2 c2) -> f16x8 {
        i32x4 wu;
#pragma unroll
        for (int dd = 0; dd < 4; ++dd) {
            const int t = q[dd] >> sh0;
            const unsigned u = (unsigned)((t & 15) | ((t & 0xF0) << 12)) | 0x64006400u;
            f16x2 qv = __builtin_bit_cast(f16x2, u);
            f16x2 q2 = qv + m1024;                   // exact: q as f16 pair
            f16x2 w  = __builtin_elementwise_fma(q2, s2, c2);
            wu[dd] = __builtin_bit_cast(int, w);
        }
        return __builtin_bit_cast(f16x8, wu);
    };

    auto COMPUTE = [&](const GD& d, int gl) {
        const int c0 = ks * 8 + gl * 2;              // local K32-chunk
        f16x8 a00 = LDSA(col, c0),      a01 = LDSA(col + 16, c0);
        f16x8 a10 = LDSA(col, c0 + 1),  a11 = LDSA(col + 16, c0 + 1);
        const _Float16 hs0 = (_Float16)d.s0, hs1 = (_Float16)d.s1;
        const _Float16 hc0 = (_Float16)(-d.z0 * d.s0);
        const _Float16 hc1 = (_Float16)(-d.z1 * d.s1);
        const f16x2 s20 = {hs0, hs0}, c20 = {hc0, hc0};
        const f16x2 s21 = {hs1, hs1}, c21 = {hc1, hc1};
        f16x8 w00 = DQ(d.qa0, s20, c20), w01 = DQ(d.qa1, s20, c20);
        f16x8 w10 = DQ(d.qb0, s21, c21), w11 = DQ(d.qb1, s21, c21);
        acc00 = __builtin_amdgcn_mfma_f32_16x16x32_f16(a00, w00, acc00, 0, 0, 0);
        acc01 = __builtin_amdgcn_mfma_f32_16x16x32_f16(a01, w00, acc01, 0, 0, 0);
        acc10 = __builtin_amdgcn_mfma_f32_16x16x32_f16(a00, w10, acc10, 0, 0, 0);
        acc11 = __builtin_amdgcn_mfma_f32_16x16x32_f16(a01, w10, acc11, 0, 0, 0);
        acc00 = __builtin_amdgcn_mfma_f32_16x16x32_f16(a10, w01, acc00, 0, 0, 0);
        acc01 = __builtin_amdgcn_mfma_f32_16x16x32_f16(a11, w01, acc01, 0, 0, 0);
        acc10 = __builtin_amdgcn_mfma_f32_16x16x32_f16(a10, w11, acc10, 0, 0, 0);
        acc11 = __builtin_amdgcn_mfma_f32_16x16x32_f16(a11, w11, acc11, 0, 0, 0);
    };

#pragma unroll
    for (int gl = 0; gl < GPW; gl += 2) {
        COMPUTE(gA, gl);
        LOADG(gA, gl + 2);
        __builtin_amdgcn_sched_barrier(0);   // loads may NOT sink past next COMPUTE
        COMPUTE(gB, gl + 1);
        LOADG(gB, gl + 3);
        __builtin_amdgcn_sched_barrier(0);
    }

    // ---- inner-kseg reduction through LDS (reuse xs) ----
    __syncthreads();
    float (*red)[64][17] = reinterpret_cast<float (*)[64][17]>(xs);
    if (ks == 1) {
#pragma unroll
        for (int e = 0; e < 4; ++e) {
            red[cw][lane][e]      = acc00[e];
            red[cw][lane][4 + e]  = acc01[e];
            red[cw][lane][8 + e]  = acc10[e];
            red[cw][lane][12 + e] = acc11[e];
        }
    }
    __syncthreads();
    if (ks == 0) {
#pragma unroll
        for (int e = 0; e < 4; ++e) {
            acc00[e] += red[cw][lane][e];
            acc01[e] += red[cw][lane][4 + e];
            acc10[e] += red[cw][lane][8 + e];
            acc11[e] += red[cw][lane][12 + e];
        }
        // D layout (verified m89/m91): col = lane&15, row = (lane>>4)*4 + r
        // NON-TEMPORAL: stream to L3, not dirty-in-local-L2 (epi reads all obs)
        _Float16* pb = partial + (size_t)ob * PART_ELEMS;
#pragma unroll
        for (int r = 0; r < 4; ++r) {
            const int t = kg * 4 + r;
            __builtin_nontemporal_store((_Float16)acc00[r], &pb[t * NDIM + n0]);
            __builtin_nontemporal_store((_Float16)acc01[r], &pb[(t + 16) * NDIM + n0]);
            __builtin_nontemporal_store((_Float16)acc10[r], &pb[t * NDIM + n0 + 16]);
            __builtin_nontemporal_store((_Float16)acc11[r], &pb[(t + 16) * NDIM + n0 + 16]);
        }
    }
}

// Epilogue: out = sum(8 f16 partials) + bias.
// 44032 f16x8 slots = 172 blocks x 256 thr; nt loads (no reuse).
__global__ __launch_bounds__(256) void awq_epi(
    const _Float16* __restrict__ part, const float* __restrict__ bias,
    float* __restrict__ out) {
    const int i = blockIdx.x * 256 + threadIdx.x;    // f16x8 slot, exact fit
    const f16x8* p = reinterpret_cast<const f16x8*>(part);
    f32x8 v = __builtin_convertvector(__builtin_nontemporal_load(&p[i]), f32x8);
#pragma unroll
    for (int o = 1; o < OUTK; ++o)
        v += __builtin_convertvector(
            __builtin_nontemporal_load(&p[(size_t)o * (PART_ELEMS / 8) + i]), f32x8);
    const int bs = i % (NDIM / 8);                   // 8-col slot within row
    const f32x4* bq = reinterpret_cast<const f32x4*>(bias) + bs * 2;
    f32x4 lo = {v[0], v[1], v[2], v[3]}, hi = {v[4], v[5], v[6], v[7]};
    lo += bq[0];
    hi += bq[1];
    f32x4* oq = reinterpret_cast<f32x4*>(out) + (size_t)i * 2;
    oq[0] = lo;
    oq[1] = hi;
}

// Fallback (ws too small): round-7 kernel, bf16 path, no ws usage.
__global__ __launch_bounds__(256, 3) void awq_gemm_fb(
    const int* __restrict__ qw, const float* __restrict__ sc,
    const float* __restrict__ zp, const float* __restrict__ bias,
    const float* __restrict__ xf, float* __restrict__ out) {
    const int lane = threadIdx.x & 63;
    const int kseg = threadIdx.x >> 6;
    const int col  = lane & 15;
    const int kg   = lane >> 4;
    const int n    = blockIdx.x * 16 + col;
    const int sh0  = 8 * (n & 3);
    const int* qp  = qw + (n >> 2) * KP + kg * 4;
    const int r0 = col, r1 = col + 16;

    f32x4 acc0 = {0,0,0,0}, acc1 = {0,0,0,0};

    auto cvt8 = [](const float* p) {
        f32x4 u0 = *reinterpret_cast<const f32x4*>(p);
        f32x4 u1 = *reinterpret_cast<const f32x4*>(p + 4);
        s16x8 o;
#pragma unroll
        for (int e = 0; e < 4; ++e) {
            o[e]     = __builtin_bit_cast(short, __float2bfloat16(u0[e]));
            o[e + 4] = __builtin_bit_cast(short, __float2bfloat16(u1[e]));
        }
        return o;
    };

    const int g_lo = kseg * (NGRP / 4), g_hi = g_lo + (NGRP / 4);
#pragma unroll 2
    for (int g = g_lo; g < g_hi; ++g) {
        const float s = sc[g * NDIM + n];
        const float bz = -zp[g * NDIM + n] * s;
#pragma unroll
        for (int h = 0; h < 2; ++h) {
            const int chunk = 2 * g + h;
            i32x4 q = *reinterpret_cast<const i32x4*>(qp + chunk * 16);
            const float* p0 = xf + r0 * KDIM + chunk * 32 + kg * 8;
            const float* p1 = xf + r1 * KDIM + chunk * 32 + kg * 8;
            s16x8 a0 = cvt8(p0), a1 = cvt8(p1);
            s16x8 wf;
#pragma unroll
            for (int dd = 0; dd < 4; ++dd) {
                const int qd = q[dd];
                float w0 = (float)((qd >> sh0) & 15) * s + bz;
                float w1 = (float)((qd >> (sh0 + 4)) & 15) * s + bz;
                wf[2 * dd]     = __builtin_bit_cast(short, __float2bfloat16(w0));
                wf[2 * dd + 1] = __builtin_bit_cast(short, __float2bfloat16(w1));
            }
            acc0 = __builtin_amdgcn_mfma_f32_16x16x32_bf16(a0, wf, acc0, 0, 0, 0);
            acc1 = __builtin_amdgcn_mfma_f32_16x16x32_bf16(a1, wf, acc1, 0, 0, 0);
        }
    }

    __shared__ float red[3][64][9];
    if (kseg != 0) {
#pragma unroll
        for (int e = 0; e < 4; ++e) {
            red[kseg - 1][lane][e]     = acc0[e];
            red[kseg - 1][lane][4 + e] = acc1[e];
        }
    }
    __syncthreads();
    if (kseg == 0) {
#pragma unroll
        for (int ss = 0; ss < 3; ++ss)
#pragma unroll
            for (int e = 0; e < 4; ++e) {
                acc0[e] += red[ss][lane][e];
                acc1[e] += red[ss][lane][4 + e];
            }
        const float bv = bias[n];
#pragma unroll
        for (int r = 0; r < 4; ++r) {
            const int t = kg * 4 + r;
            out[t * NDIM + n]        = acc0[r] + bv;
            out[(t + 16) * NDIM + n] = acc1[r] + bv;
        }
    }
}

extern "C" void kernel_launch(void* const* d_in, const int* in_sizes, int n_in,
                              void* d_out, int out_size, void* d_ws, size_t ws_size,
                              hipStream_t stream) {
    const float* x    = (const float*)d_in[0];
    const int*   qw   = (const int*)d_in[1];
    const float* sc   = (const float*)d_in[2];
    const float* zp   = (const float*)d_in[3];
    const float* bias = (const float*)d_in[4];
    float*       out  = (float*)d_out;

    const size_t part_bytes = (size_t)OUTK * PART_ELEMS * sizeof(_Float16); // ~5.6 MB

    if (ws_size >= part_bytes) {
        _Float16* part = (_Float16*)d_ws;
        awq_gemm2<<<NBLK_C * OUTK, 512, 0, stream>>>(qw, sc, zp, x, part);
        awq_epi<<<PART_ELEMS / 8 / 256, 256, 0, stream>>>(part, bias, out);
    } else {
        awq_gemm_fb<<<NDIM / 16, 256, 0, stream>>>(qw, sc, zp, bias, x, out);
    }
}

// Round 27
// 17.947 us; speedup vs baseline: 1.0472x; 1.0472x over previous
//
#include <hip/hip_runtime.h>
#include <hip/hip_bf16.h>

#define TOKENS 32
#define KDIM   4096
#define NDIM   11008
#define GSZ    64
#define KP     (KDIM/2)          // qweight row length in int32 (2048)
#define NGRP   (KDIM/GSZ)        // 64 groups
#define OUTK   8                 // K-splits across blocks (== 8 XCDs, ob=bi&7)
#define BLK_COLS 128             // 4 colWaves * 32 cols
#define NBLK_C (NDIM/BLK_COLS)   // 86
#define KSLICE (KDIM/OUTK)       // 512 k per block
#define GPW    (KSLICE/2/GSZ)    // 4 groups per wave (2 inner ksegs)
#define PART_ELEMS (TOKENS*NDIM) // 352256

typedef float  f32x4 __attribute__((ext_vector_type(4)));
typedef float  f32x8 __attribute__((ext_vector_type(8)));
typedef int    i32x4 __attribute__((ext_vector_type(4)));
typedef short  s16x8 __attribute__((ext_vector_type(8)));
typedef _Float16 f16x2 __attribute__((ext_vector_type(2)));
typedef _Float16 f16x8 __attribute__((ext_vector_type(8)));

// FINAL (r27 = r19/r23/r25 exact; best measured 18.1us, verified 3x).
// Structure: 2 kernels. gemm (688 blocks = 86 colGroups x 8 outer-ksegs,
// 512 thr = 8 waves) writes f16 partials nt; epi sums 8 partials + bias.
// Every decision is locked by a measured failed alternative:
//  - ob = bi&7 (one K-slice per XCD; q 2.8MB + sc/zp 0.7MB + x 64KB < 4MB L2).
//    Remapping off the XCD axis spills sc/zp -> r15: 27us.
//  - 8-way K-reduction MUST be a separate kernel on CDNA4: fence-fused r11
//    300us (threadfence = L2 writeback storm); colocated finisher r15 27us;
//    f32 atomics into out r22 26us (cross-XCD RMW serializes); fence-free
//    finisher r24 RACES (vmcnt(0) drains the CU, not cross-XCD visibility).
//  - nt partial stores (r19, -0.8us: no cross-XCD dirty-line snoops in epi).
//  - f16 partials (r17, -1.3us: halves partial traffic; ~5e-3 zero-mean err).
//  - f16 packed dequant, exact -1024 subtract (r13, -0.9us). Never fold a
//    large constant into the FMA bias (r5: ~s/2 group offset fails absmax).
//  - 512thr/8-wave/OUTK=8 shape (r14 OUTK4, r16 4-wave: less TLP, slower).
//  - K-loop is TLP-saturated at 5.4 waves/SIMD: r12 LDS-only, r18 async-DMA
//    dbuf, r26 sched_barrier ILP-pinning all neutral — per-wave latency is
//    hidden by wave-level parallelism; per-wave ILP buys nothing.
__global__ __launch_bounds__(512, 2) void awq_gemm2(
    const int* __restrict__ qw, const float* __restrict__ sc,
    const float* __restrict__ zp, const float* __restrict__ xf,
    _Float16* __restrict__ partial) {
    __shared__ unsigned short xs[TOKENS * KSLICE];   // 32 KB (reused for reduce)

    const int tid  = threadIdx.x;
    const int lane = tid & 63;
    const int wid  = tid >> 6;       // 0..7
    const int cw   = wid & 3;        // colWave
    const int ks   = wid >> 2;       // inner kseg 0..1
    const int ob   = blockIdx.x & 7;         // outer kseg == XCD
    const int bc   = blockIdx.x >> 3;        // col group 0..85
    const int K0   = ob * KSLICE;

    const int col  = lane & 15;
    const int kg   = lane >> 4;                      // k-subgroup 0..3
    const int n0   = bc * BLK_COLS + cw * 32 + col;  // colset-0 column
    const int sh0  = 8 * (n0 & 3);
    const int* qp0 = qw + (n0 >> 2) * KP + kg * 4;   // colset-1 = +4*KP ints

    struct GD { float s0, z0, s1, z1; i32x4 qa0, qa1, qb0, qb1; };

    auto LOADG = [&](GD& d, int gl) {
        gl = gl < GPW ? gl : GPW - 1;                // clamp prefetch overhang
        const int gg = ob * (NGRP / OUTK) + ks * GPW + gl;  // global group
        d.s0 = sc[gg * NDIM + n0];        d.z0 = zp[gg * NDIM + n0];
        d.s1 = sc[gg * NDIM + n0 + 16];   d.z1 = zp[gg * NDIM + n0 + 16];
        const int* q = qp0 + gg * 32;
        d.qa0 = *reinterpret_cast<const i32x4*>(q);
        d.qa1 = *reinterpret_cast<const i32x4*>(q + 16);
        d.qb0 = *reinterpret_cast<const i32x4*>(q + 4 * KP);
        d.qb1 = *reinterpret_cast<const i32x4*>(q + 4 * KP + 16);
    };

    // ---- q-prefetch for groups 0/1 issued BEFORE staging ----
    GD gA, gB;
    LOADG(gA, 0);
    LOADG(gB, 1);

    // ---- stage x slice: f32 global -> f16 swizzled LDS (32KB) ----
#pragma unroll
    for (int it = 0; it < 4; ++it) {
        const int lin  = it * 8192 + tid * 16;       // byte offset in f16 slice
        const int tok  = lin >> 10;
        const int kloc = (lin & 1023) >> 1;
        const float* xp = xf + tok * KDIM + K0 + kloc;
        f32x4 u0 = *reinterpret_cast<const f32x4*>(xp);
        f32x4 u1 = *reinterpret_cast<const f32x4*>(xp + 4);
        s16x8 v;
#pragma unroll
        for (int e = 0; e < 4; ++e) {
            v[e]     = __builtin_bit_cast(short, (_Float16)u0[e]);
            v[e + 4] = __builtin_bit_cast(short, (_Float16)u1[e]);
        }
        *reinterpret_cast<s16x8*>(
            reinterpret_cast<char*>(xs) + (lin ^ ((tok & 7) << 4))) = v;
    }
    __syncthreads();

    f32x4 acc00 = {0,0,0,0}, acc01 = {0,0,0,0};      // [colset][Mtile]
    f32x4 acc10 = {0,0,0,0}, acc11 = {0,0,0,0};

    auto LDSA = [&](int tok, int c) -> f16x8 {       // a-frag from swizzled LDS
        const int inrow = ((c << 6) + (kg << 4)) ^ ((tok & 7) << 4);
        return *reinterpret_cast<const f16x8*>(
            reinterpret_cast<const char*>(xs) + (tok << 10) + inrow);
    };

    const f16x2 m1024 = {(_Float16)(-1024.0f), (_Float16)(-1024.0f)};

    auto DQ = [&](const i32x4& q, f16x2 s2, f16x2 c2) -> f16x8 {
        i32x4 wu;
#pragma unroll
        for (int dd = 0; dd < 4; ++dd) {
            const int t = q[dd] >> sh0;
            const unsigned u = (unsigned)((t & 15) | ((t & 0xF0) << 12)) | 0x64006400u;
            f16x2 qv = __builtin_bit_cast(f16x2, u);
            f16x2 q2 = qv + m1024;                   // exact: q as f16 pair
            f16x2 w  = __builtin_elementwise_fma(q2, s2, c2);
            wu[dd] = __builtin_bit_cast(int, w);
        }
        return __builtin_bit_cast(f16x8, wu);
    };

    auto COMPUTE = [&](const GD& d, int gl) {
        const int c0 = ks * 8 + gl * 2;              // local K32-chunk
        f16x8 a00 = LDSA(col, c0),      a01 = LDSA(col + 16, c0);
        f16x8 a10 = LDSA(col, c0 + 1),  a11 = LDSA(col + 16, c0 + 1);
        const _Float16 hs0 = (_Float16)d.s0, hs1 = (_Float16)d.s1;
        const _Float16 hc0 = (_Float16)(-d.z0 * d.s0);
        const _Float16 hc1 = (_Float16)(-d.z1 * d.s1);
        const f16x2 s20 = {hs0, hs0}, c20 = {hc0, hc0};
        const f16x2 s21 = {hs1, hs1}, c21 = {hc1, hc1};
        f16x8 w00 = DQ(d.qa0, s20, c20), w01 = DQ(d.qa1, s20, c20);
        f16x8 w10 = DQ(d.qb0, s21, c21), w11 = DQ(d.qb1, s21, c21);
        acc00 = __builtin_amdgcn_mfma_f32_16x16x32_f16(a00, w00, acc00, 0, 0, 0);
        acc01 = __builtin_amdgcn_mfma_f32_16x16x32_f16(a01, w00, acc01, 0, 0, 0);
        acc10 = __builtin_amdgcn_mfma_f32_16x16x32_f16(a00, w10, acc10, 0, 0, 0);
        acc11 = __builtin_amdgcn_mfma_f32_16x16x32_f16(a01, w10, acc11, 0, 0, 0);
        acc00 = __builtin_amdgcn_mfma_f32_16x16x32_f16(a10, w01, acc00, 0, 0, 0);
        acc01 = __builtin_amdgcn_mfma_f32_16x16x32_f16(a11, w01, acc01, 0, 0, 0);
        acc10 = __builtin_amdgcn_mfma_f32_16x16x32_f16(a10, w11, acc10, 0, 0, 0);
        acc11 = __builtin_amdgcn_mfma_f32_16x16x32_f16(a11, w11, acc11, 0, 0, 0);
    };

#pragma unroll
    for (int gl = 0; gl < GPW; gl += 2) {
        COMPUTE(gA, gl);     LOADG(gA, gl + 2);
        COMPUTE(gB, gl + 1); LOADG(gB, gl + 3);
    }

    // ---- inner-kseg reduction through LDS (reuse xs) ----
    __syncthreads();
    float (*red)[64][17] = reinterpret_cast<float (*)[64][17]>(xs);
    if (ks == 1) {
#pragma unroll
        for (int e = 0; e < 4; ++e) {
            red[cw][lane][e]      = acc00[e];
            red[cw][lane][4 + e]  = acc01[e];
            red[cw][lane][8 + e]  = acc10[e];
            red[cw][lane][12 + e] = acc11[e];
        }
    }
    __syncthreads();
    if (ks == 0) {
#pragma unroll
        for (int e = 0; e < 4; ++e) {
            acc00[e] += red[cw][lane][e];
            acc01[e] += red[cw][lane][4 + e];
            acc10[e] += red[cw][lane][8 + e];
            acc11[e] += red[cw][lane][12 + e];
        }
        // D layout (verified m89/m91): col = lane&15, row = (lane>>4)*4 + r
        // NON-TEMPORAL: stream to L3, not dirty-in-local-L2 (epi reads all obs)
        _Float16* pb = partial + (size_t)ob * PART_ELEMS;
#pragma unroll
        for (int r = 0; r < 4; ++r) {
            const int t = kg * 4 + r;
            __builtin_nontemporal_store((_Float16)acc00[r], &pb[t * NDIM + n0]);
            __builtin_nontemporal_store((_Float16)acc01[r], &pb[(t + 16) * NDIM + n0]);
            __builtin_nontemporal_store((_Float16)acc10[r], &pb[t * NDIM + n0 + 16]);
            __builtin_nontemporal_store((_Float16)acc11[r], &pb[(t + 16) * NDIM + n0 + 16]);
        }
    }
}

// Epilogue: out = sum(8 f16 partials) + bias.
// 44032 f16x8 slots = 172 blocks x 256 thr; nt loads (no reuse).
__global__ __launch_bounds__(256) void awq_epi(
    const _Float16* __restrict__ part, const float* __restrict__ bias,
    float* __restrict__ out) {
    const int i = blockIdx.x * 256 + threadIdx.x;    // f16x8 slot, exact fit
    const f16x8* p = reinterpret_cast<const f16x8*>(part);
    f32x8 v = __builtin_convertvector(__builtin_nontemporal_load(&p[i]), f32x8);
#pragma unroll
    for (int o = 1; o < OUTK; ++o)
        v += __builtin_convertvector(
            __builtin_nontemporal_load(&p[(size_t)o * (PART_ELEMS / 8) + i]), f32x8);
    const int bs = i % (NDIM / 8);                   // 8-col slot within row
    const f32x4* bq = reinterpret_cast<const f32x4*>(bias) + bs * 2;
    f32x4 lo = {v[0], v[1], v[2], v[3]}, hi = {v[4], v[5], v[6], v[7]};
    lo += bq[0];
    hi += bq[1];
    f32x4* oq = reinterpret_cast<f32x4*>(out) + (size_t)i * 2;
    oq[0] = lo;
    oq[1] = hi;
}

// Fallback (ws too small): round-7 kernel, bf16 path, no ws usage.
__global__ __launch_bounds__(256, 3) void awq_gemm_fb(
    const int* __restrict__ qw, const float* __restrict__ sc,
    const float* __restrict__ zp, const float* __restrict__ bias,
    const float* __restrict__ xf, float* __restrict__ out) {
    const int lane = threadIdx.x & 63;
    const int kseg = threadIdx.x >> 6;
    const int col  = lane & 15;
    const int kg   = lane >> 4;
    const int n    = blockIdx.x * 16 + col;
    const int sh0  = 8 * (n & 3);
    const int* qp  = qw + (n >> 2) * KP + kg * 4;
    const int r0 = col, r1 = col + 16;

    f32x4 acc0 = {0,0,0,0}, acc1 = {0,0,0,0};

    auto cvt8 = [](const float* p) {
        f32x4 u0 = *reinterpret_cast<const f32x4*>(p);
        f32x4 u1 = *reinterpret_cast<const f32x4*>(p + 4);
        s16x8 o;
#pragma unroll
        for (int e = 0; e < 4; ++e) {
            o[e]     = __builtin_bit_cast(short, __float2bfloat16(u0[e]));
            o[e + 4] = __builtin_bit_cast(short, __float2bfloat16(u1[e]));
        }
        return o;
    };

    const int g_lo = kseg * (NGRP / 4), g_hi = g_lo + (NGRP / 4);
#pragma unroll 2
    for (int g = g_lo; g < g_hi; ++g) {
        const float s = sc[g * NDIM + n];
        const float bz = -zp[g * NDIM + n] * s;
#pragma unroll
        for (int h = 0; h < 2; ++h) {
            const int chunk = 2 * g + h;
            i32x4 q = *reinterpret_cast<const i32x4*>(qp + chunk * 16);
            const float* p0 = xf + r0 * KDIM + chunk * 32 + kg * 8;
            const float* p1 = xf + r1 * KDIM + chunk * 32 + kg * 8;
            s16x8 a0 = cvt8(p0), a1 = cvt8(p1);
            s16x8 wf;
#pragma unroll
            for (int dd = 0; dd < 4; ++dd) {
                const int qd = q[dd];
                float w0 = (float)((qd >> sh0) & 15) * s + bz;
                float w1 = (float)((qd >> (sh0 + 4)) & 15) * s + bz;
                wf[2 * dd]     = __builtin_bit_cast(short, __float2bfloat16(w0));
                wf[2 * dd + 1] = __builtin_bit_cast(short, __float2bfloat16(w1));
            }
            acc0 = __builtin_amdgcn_mfma_f32_16x16x32_bf16(a0, wf, acc0, 0, 0, 0);
            acc1 = __builtin_amdgcn_mfma_f32_16x16x32_bf16(a1, wf, acc1, 0, 0, 0);
        }
    }

    __shared__ float red[3][64][9];
    if (kseg != 0) {
#pragma unroll
        for (int e = 0; e < 4; ++e) {
            red[kseg - 1][lane][e]     = acc0[e];
            red[kseg - 1][lane][4 + e] = acc1[e];
        }
    }
    __syncthreads();
    if (kseg == 0) {
#pragma unroll
        for (int ss = 0; ss < 3; ++ss)
#pragma unroll
            for (int e = 0; e < 4; ++e) {
                acc0[e] += red[ss][lane][e];
                acc1[e] += red[ss][lane][4 + e];
            }
        const float bv = bias[n];
#pragma unroll
        for (int r = 0; r < 4; ++r) {
            const int t = kg * 4 + r;
            out[t * NDIM + n]        = acc0[r] + bv;
            out[(t + 16) * NDIM + n] = acc1[r] + bv;
        }
    }
}

extern "C" void kernel_launch(void* const* d_in, const int* in_sizes, int n_in,
                              void* d_out, int out_size, void* d_ws, size_t ws_size,
                              hipStream_t stream) {
    const float* x    = (const float*)d_in[0];
    const int*   qw   = (const int*)d_in[1];
    const float* sc   = (const float*)d_in[2];
    const float* zp   = (const float*)d_in[3];
    const float* bias = (const float*)d_in[4];
    float*       out  = (float*)d_out;

    const size_t part_bytes = (size_t)OUTK * PART_ELEMS * sizeof(_Float16); // ~5.6 MB

    if (ws_size >= part_bytes) {
        _Float16* part = (_Float16*)d_ws;
        awq_gemm2<<<NBLK_C * OUTK, 512, 0, stream>>>(qw, sc, zp, x, part);
        awq_epi<<<PART_ELEMS / 8 / 256, 256, 0, stream>>>(part, bias, out);
    } else {
        awq_gemm_fb<<<NDIM / 16, 256, 0, stream>>>(qw, sc, zp, bias, x, out);
    }
}